// Round 1
// 433.169 us; speedup vs baseline: 1.0073x; 1.0073x over previous
//
#include <hip/hip_runtime.h>
#include <math.h>

// B=8, N=16, D=128, H=W=64 -> G=128 groups, K=4096 tokens/group.
// keys GEMM collapses: attn_k = q_tilde.x_k + c, q_tilde = Wk^T(Wq mean+bq),
// c = query.bk. Logits ~ +-1 -> no-max softmax safe. Two x passes; measured
// (R6): pass 1 fetches ~140 MB, pass 2 ~132 MB (L3 serves the rest).
//
// HARD-WON RULE (R5: 1238us, R6: 650us vs R4: ~136us kernel time): NO
// agent-scope acquire/release fences -- they L2-writeback/invalidate per use
// on non-coherent XCD L2s. All cross-block dataflow via kernel boundaries;
// only relaxed atomicAdd within a kernel.
//
// R7 (this round): k3 keeps its x tile in REGISTERS across the softmax
// barrier instead of LDS round-tripping it (xs[D][65] deleted). LDS
// wave-instructions/block ~420 -> ~100, LDS 41.5KB -> 14.8KB (3 -> 6+
// blocks/CU). k3 group order reversed (serpentine vs k1's ascending pass)
// for L3 LRU reuse.
#define G 128
#define D 128
#define K 4096
#define CK 64

// k1: meanacc[g][d] = sum_k mask[g][k]*x[g][d][k].  One wave per d-row,
// 16 float4 x-loads fma'd against int4 mask loads (L1-shared by the 4 waves).
// No LDS -> occupancy at wave cap. Block s==0 zeroes k3's atomic targets.
__global__ __launch_bounds__(256) void k1_mean(const float* __restrict__ x,
                                               const int* __restrict__ mask,
                                               float* __restrict__ meanacc,
                                               float* __restrict__ oacc,
                                               float* __restrict__ denomv) {
  const int g = blockIdx.x >> 5, s = blockIdx.x & 31;
  const int tid = threadIdx.x;
  if (s == 0) {  // visible to k3 via kernel boundary
    if (tid < D) oacc[g * D + tid] = 0.0f;
    if (tid == D) denomv[g] = 0.0f;
  }
  const int wid = tid >> 6, lane = tid & 63;
  const int d = s * 4 + wid;
  const float4* x4 = (const float4*)(x + ((size_t)g * D + d) * K);
  const int4* m4 = (const int4*)(mask + (size_t)g * K);
  float4 acc = make_float4(0.f, 0.f, 0.f, 0.f);
#pragma unroll
  for (int it = 0; it < K / 256; ++it) {  // 16 iterations
    float4 a = x4[it * 64 + lane];
    int4 mi = m4[it * 64 + lane];
    acc.x += a.x * (float)mi.x;
    acc.y += a.y * (float)mi.y;
    acc.z += a.z * (float)mi.z;
    acc.w += a.w * (float)mi.w;
  }
  float sum = acc.x + acc.y + acc.z + acc.w;
#pragma unroll
  for (int o = 32; o > 0; o >>= 1) sum += __shfl_down(sum, o, 64);
  if (lane == 0) meanacc[g * D + d] = sum;
}

// k2: per group: cnt, mean, query = Wq*mean+bq, qt = Wk^T query, c = query.bk
// Wq matvec is per-thread-contiguous -> float4 loads (32 iters, pipelined).
__global__ __launch_bounds__(128) void k2_query(
    const float* __restrict__ meanacc, const int* __restrict__ mask,
    const float* __restrict__ Wq, const float* __restrict__ bq,
    const float* __restrict__ Wk, const float* __restrict__ bk,
    float* __restrict__ qt, float* __restrict__ cvec) {
  __shared__ __align__(16) float mean_s[D];
  __shared__ float query_s[D], red[D];
  const int g = blockIdx.x, t = threadIdx.x;
  const int4* m4 = (const int4*)(mask + (size_t)g * K);
  int csum = 0;
  for (int i = t; i < K / 4; i += 128) {
    int4 v = m4[i];
    csum += v.x + v.y + v.z + v.w;
  }
  red[t] = (float)csum;
  __syncthreads();
  for (int o = 64; o > 0; o >>= 1) {
    if (t < o) red[t] += red[t + o];
    __syncthreads();
  }
  const float cnt = red[0];
  mean_s[t] = meanacc[g * D + t] / cnt;
  __syncthreads();
  float q = bq[t];
  {
    const float4* wq4 = (const float4*)(Wq + (size_t)t * D);
    const float4* ms4 = (const float4*)mean_s;
#pragma unroll
    for (int dc = 0; dc < D / 4; ++dc) {
      float4 w = wq4[dc], m = ms4[dc];
      q += w.x * m.x + w.y * m.y + w.z * m.z + w.w * m.w;
    }
  }
  query_s[t] = q;
  __syncthreads();
  red[t] = q * bk[t];
  __syncthreads();
  for (int o = 64; o > 0; o >>= 1) {
    if (t < o) red[t] += red[t + o];
    __syncthreads();
  }
  if (t == 0) cvec[g] = red[0];
  float qq = 0.f;
#pragma unroll 8
  for (int d = 0; d < D; ++d) qq += query_s[d] * Wk[d * D + t];
  qt[g * D + t] = qq;
}

// k3: fused logits + exp + pool. Block = (g, 64-k chunk), g DESCENDING
// (serpentine vs k1 for L3 reuse). Thread (j=tid&15, owner=tid>>4) owns
// k-quad 4j..4j+3 and d-rows owner+16*it (it=0..7); the 8 float4 x values
// stay in REGISTERS across both barriers -- no xs LDS tile.
//   phase 1: load v[8], accumulate logit partials vs qt (L1-hot scalars)
//   phase 2: 64 threads combine 16 owner-partials, mask+exp -> wsm, denom
//   phase 3: per-thread 4-FMA pool partial -> part3[d][j]; 128 threads
//            reduce rows via b128 (pad 20 -> aligned, 8 words/bank uniform).
// part2 pad 17: write banks (4j+17r+owner)%32 -> 2-way (free).
__global__ __launch_bounds__(256) void k3_fused(
    const float* __restrict__ x, const int* __restrict__ mask,
    const float* __restrict__ qt, const float* __restrict__ cvec,
    float* __restrict__ oacc, float* __restrict__ denomv) {
  __shared__ float part2[CK][17];                  // [k][owner] logit partials
  __shared__ __align__(16) float wsm[CK];          // softmax weights
  __shared__ __align__(16) float part3[D][20];     // [d][j] pool partials
  const int g = (G - 1) - (int)(blockIdx.x >> 6);  // serpentine
  const int k0 = (blockIdx.x & 63) * CK;
  const int tid = threadIdx.x;
  const int j = tid & 15, owner = tid >> 4;
  const float4* xg = (const float4*)(x + (size_t)g * D * K + k0);
  const float* qtg = qt + g * D;
  float4 v[8];
  float p0 = 0.f, p1 = 0.f, p2 = 0.f, p3 = 0.f;
#pragma unroll
  for (int it = 0; it < 8; ++it) {
    const int dd = owner + 16 * it;
    v[it] = xg[(size_t)dd * (K / 4) + j];
    const float qv = qtg[dd];  // L1-hot scalar
    p0 += qv * v[it].x;
    p1 += qv * v[it].y;
    p2 += qv * v[it].z;
    p3 += qv * v[it].w;
  }
  part2[4 * j + 0][owner] = p0;
  part2[4 * j + 1][owner] = p1;
  part2[4 * j + 2][owner] = p2;
  part2[4 * j + 3][owner] = p3;
  __syncthreads();
  if (tid < CK) {  // combine 16 partials, exp, mask; reduce denom partial
    float l = 0.f;
#pragma unroll
    for (int o = 0; o < 16; ++o) l += part2[tid][o];
    const float scale = 0.08838834764831845f;  // 1/sqrt(128)
    l = (l + cvec[g]) * scale;
    float w = mask[(size_t)g * K + k0 + tid] ? __expf(l) : 0.f;
    wsm[tid] = w;
#pragma unroll
    for (int o = 32; o > 0; o >>= 1) w += __shfl_down(w, o, 64);
    if (tid == 0) atomicAdd(denomv + g, w);
  }
  __syncthreads();
  {  // pool partials straight from the register tile
    const float4 wv = *(const float4*)&wsm[4 * j];
#pragma unroll
    for (int it = 0; it < 8; ++it) {
      const int dd = owner + 16 * it;
      part3[dd][j] =
          wv.x * v[it].x + wv.y * v[it].y + wv.z * v[it].z + wv.w * v[it].w;
    }
  }
  __syncthreads();
  if (tid < D) {  // reduce 16 j-partials per d-row, b128 conflict-free
    const float4* r4 = (const float4*)part3[tid];
    float4 a = r4[0], b = r4[1], c = r4[2], e = r4[3];
    float o = a.x + a.y + a.z + a.w + b.x + b.y + b.z + b.w + c.x + c.y + c.z +
              c.w + e.x + e.y + e.z + e.w;
    atomicAdd(oacc + g * D + tid, o);
  }
}

// k4: out = oacc / denom
__global__ __launch_bounds__(256) void k4_norm(const float* __restrict__ oacc,
                                               const float* __restrict__ denomv,
                                               float* __restrict__ out) {
  int i = blockIdx.x * 256 + threadIdx.x;  // exactly G*D
  out[i] = oacc[i] / denomv[i >> 7];
}

extern "C" void kernel_launch(void* const* d_in, const int* in_sizes, int n_in,
                              void* d_out, int out_size, void* d_ws,
                              size_t ws_size, hipStream_t stream) {
  const float* x = (const float*)d_in[0];
  const int* mask = (const int*)d_in[1];
  const float* Wq = (const float*)d_in[2];
  const float* bq = (const float*)d_in[3];
  const float* Wk = (const float*)d_in[4];
  const float* bk = (const float*)d_in[5];
  float* out = (float*)d_out;

  float* ws = (float*)d_ws;
  float* meanacc = ws;                 // G*D
  float* qt = ws + G * D;              // G*D
  float* cvec = ws + 2 * G * D;        // G
  float* oacc = ws + 2 * G * D + G;    // G*D
  float* denomv = ws + 3 * G * D + G;  // G

  k1_mean<<<G * 32, 256, 0, stream>>>(x, mask, meanacc, oacc, denomv);
  k2_query<<<G, 128, 0, stream>>>(meanacc, mask, Wq, bq, Wk, bk, qt, cvec);
  k3_fused<<<G * (K / CK), 256, 0, stream>>>(x, mask, qt, cvec, oacc, denomv);
  k4_norm<<<(G * D) / 256, 256, 0, stream>>>(oacc, denomv, out);
}

// Round 2
// 418.741 us; speedup vs baseline: 1.0420x; 1.0345x over previous
//
#include <hip/hip_runtime.h>
#include <math.h>

// B=8, N=16, D=128, H=W=64 -> G=128 groups, K=4096 tokens/group.
// keys GEMM collapses: attn_k = q_tilde.x_k + c, q_tilde = Wk^T(Wq mean+bq),
// c = query.bk. Logits ~ +-1 -> no-max softmax safe. Two x passes (mean needs
// all of x before logits exist) -- ~400 MB HBM floor ~= 62 us.
//
// HARD-WON RULE (R5: 1238us, R6: 650us vs R4: ~136us kernel time): NO
// agent-scope acquire/release fences -- they L2-writeback/invalidate per use
// on non-coherent XCD L2s. All cross-block dataflow via kernel boundaries.
//
// R7: k3 x-tile in registers across barriers (LDS 41.5->14.8KB): neutral
// (-3us) -> k3 was not LDS-bound.
// R8 (this round): ZERO atomics. k3's 1.06M device-scope atomicAdds
// (1024 serialized RMWs per oacc cache line at the cross-XCD coherence
// point) replaced by plain-store partials opart[g][chunk][d] (4 MB) +
// dpart[g][chunk]; k4 reduces 64 partials and divides. k1 no longer
// pre-zeroes; its s==0 block wave-reduces the mask count it already loads,
// so k2 drops its mask pass.
#define G 128
#define D 128
#define K 4096
#define CK 64
#define NC (K / CK)  // 64 chunks per group

// k1: meanacc[g][d] = sum_k mask[g][k]*x[g][d][k].  One wave per d-row,
// 16 float4 x-loads fma'd against int4 mask loads (L1-shared by the 4 waves).
// No LDS -> occupancy at wave cap. Each wave covers the whole 16KB mask row,
// so block s==0 wave 0 reduces its int partials into fcnt[g] for free.
__global__ __launch_bounds__(256) void k1_mean(const float* __restrict__ x,
                                               const int* __restrict__ mask,
                                               float* __restrict__ meanacc,
                                               float* __restrict__ fcnt) {
  const int g = blockIdx.x >> 5, s = blockIdx.x & 31;
  const int tid = threadIdx.x;
  const int wid = tid >> 6, lane = tid & 63;
  const int d = s * 4 + wid;
  const float4* x4 = (const float4*)(x + ((size_t)g * D + d) * K);
  const int4* m4 = (const int4*)(mask + (size_t)g * K);
  float4 acc = make_float4(0.f, 0.f, 0.f, 0.f);
  int cs = 0;
#pragma unroll
  for (int it = 0; it < K / 256; ++it) {  // 16 iterations
    float4 a = x4[it * 64 + lane];
    int4 mi = m4[it * 64 + lane];
    acc.x += a.x * (float)mi.x;
    acc.y += a.y * (float)mi.y;
    acc.z += a.z * (float)mi.z;
    acc.w += a.w * (float)mi.w;
    cs += mi.x + mi.y + mi.z + mi.w;
  }
  float sum = acc.x + acc.y + acc.z + acc.w;
#pragma unroll
  for (int o = 32; o > 0; o >>= 1) sum += __shfl_down(sum, o, 64);
  if (lane == 0) meanacc[g * D + d] = sum;
  if (s == 0 && wid == 0) {  // wave 0 spans all 1024 int4s of the mask row
#pragma unroll
    for (int o = 32; o > 0; o >>= 1) cs += __shfl_down(cs, o, 64);
    if (lane == 0) fcnt[g] = (float)cs;
  }
}

// k2: per group: mean, query = Wq*mean+bq, qt = Wk^T query, c = query.bk
// Wq matvec per-thread-contiguous float4; Wk^T matvec coalesced across t.
__global__ __launch_bounds__(128) void k2_query(
    const float* __restrict__ meanacc, const float* __restrict__ fcnt,
    const float* __restrict__ Wq, const float* __restrict__ bq,
    const float* __restrict__ Wk, const float* __restrict__ bk,
    float* __restrict__ qt, float* __restrict__ cvec) {
  __shared__ __align__(16) float mean_s[D];
  __shared__ float query_s[D], red[D];
  const int g = blockIdx.x, t = threadIdx.x;
  mean_s[t] = meanacc[g * D + t] / fcnt[g];
  __syncthreads();
  float q = bq[t];
  {
    const float4* wq4 = (const float4*)(Wq + (size_t)t * D);
    const float4* ms4 = (const float4*)mean_s;
#pragma unroll
    for (int dc = 0; dc < D / 4; ++dc) {
      float4 w = wq4[dc], m = ms4[dc];
      q += w.x * m.x + w.y * m.y + w.z * m.z + w.w * m.w;
    }
  }
  query_s[t] = q;
  red[t] = q * bk[t];
  __syncthreads();
  for (int o = 64; o > 0; o >>= 1) {
    if (t < o) red[t] += red[t + o];
    __syncthreads();
  }
  if (t == 0) cvec[g] = red[0];
  float qq = 0.f;
#pragma unroll 8
  for (int d = 0; d < D; ++d) qq += query_s[d] * Wk[d * D + t];
  qt[g * D + t] = qq;
}

// k3: fused logits + exp + pool. Block = (g, 64-k chunk), g DESCENDING
// (serpentine vs k1 for L3 reuse). Thread (j=tid&15, owner=tid>>4) owns
// k-quad 4j..4j+3 and d-rows owner+16*it (it=0..7); the 8 float4 x values
// stay in REGISTERS across both barriers -- no xs LDS tile.
//   phase 1: load v[8], accumulate logit partials vs qt (L1-hot scalars)
//   phase 2: 64 threads combine 16 owner-partials, mask+exp -> wsm;
//            denom partial -> dpart[g][chunk] (plain store)
//   phase 3: per-thread 4-FMA pool partial -> part3[d][j]; 128 threads
//            reduce rows via b128 -> opart[g][chunk][d] (plain store).
// part2 pad 17: write banks 2-way (free). part3 pad 20: b128-aligned rows.
__global__ __launch_bounds__(256) void k3_fused(
    const float* __restrict__ x, const int* __restrict__ mask,
    const float* __restrict__ qt, const float* __restrict__ cvec,
    float* __restrict__ opart, float* __restrict__ dpart) {
  __shared__ float part2[CK][17];                  // [k][owner] logit partials
  __shared__ __align__(16) float wsm[CK];          // softmax weights
  __shared__ __align__(16) float part3[D][20];     // [d][j] pool partials
  const int g = (G - 1) - (int)(blockIdx.x >> 6);  // serpentine
  const int bc = blockIdx.x & 63;
  const int k0 = bc * CK;
  const int tid = threadIdx.x;
  const int j = tid & 15, owner = tid >> 4;
  const float4* xg = (const float4*)(x + (size_t)g * D * K + k0);
  const float* qtg = qt + g * D;
  float4 v[8];
  float p0 = 0.f, p1 = 0.f, p2 = 0.f, p3 = 0.f;
#pragma unroll
  for (int it = 0; it < 8; ++it) {
    const int dd = owner + 16 * it;
    v[it] = xg[(size_t)dd * (K / 4) + j];
    const float qv = qtg[dd];  // L1-hot scalar
    p0 += qv * v[it].x;
    p1 += qv * v[it].y;
    p2 += qv * v[it].z;
    p3 += qv * v[it].w;
  }
  part2[4 * j + 0][owner] = p0;
  part2[4 * j + 1][owner] = p1;
  part2[4 * j + 2][owner] = p2;
  part2[4 * j + 3][owner] = p3;
  __syncthreads();
  if (tid < CK) {  // combine 16 partials, exp, mask; denom partial store
    float l = 0.f;
#pragma unroll
    for (int o = 0; o < 16; ++o) l += part2[tid][o];
    const float scale = 0.08838834764831845f;  // 1/sqrt(128)
    l = (l + cvec[g]) * scale;
    float w = mask[(size_t)g * K + k0 + tid] ? __expf(l) : 0.f;
    wsm[tid] = w;
#pragma unroll
    for (int o = 32; o > 0; o >>= 1) w += __shfl_down(w, o, 64);
    if (tid == 0) dpart[g * NC + bc] = w;
  }
  __syncthreads();
  {  // pool partials straight from the register tile
    const float4 wv = *(const float4*)&wsm[4 * j];
#pragma unroll
    for (int it = 0; it < 8; ++it) {
      const int dd = owner + 16 * it;
      part3[dd][j] =
          wv.x * v[it].x + wv.y * v[it].y + wv.z * v[it].z + wv.w * v[it].w;
    }
  }
  __syncthreads();
  if (tid < D) {  // reduce 16 j-partials per d-row, b128 conflict-free
    const float4* r4 = (const float4*)part3[tid];
    float4 a = r4[0], b = r4[1], c = r4[2], e = r4[3];
    float o = a.x + a.y + a.z + a.w + b.x + b.y + b.z + b.w + c.x + c.y + c.z +
              c.w + e.x + e.y + e.z + e.w;
    opart[(size_t)(g * NC + bc) * D + tid] = o;
  }
}

// k4: per group, reduce 64 chunk-partials and normalize.
// Reads 32KB/block coalesced (256B rows, 512B stride); 4MB total.
__global__ __launch_bounds__(256) void k4_reduce(
    const float* __restrict__ opart, const float* __restrict__ dpart,
    float* __restrict__ out) {
  __shared__ float red[256];
  __shared__ float dsum_s;
  const int g = blockIdx.x, tid = threadIdx.x;
  if (tid < 64) {  // wave 0: denominator
    float w = dpart[g * NC + tid];
#pragma unroll
    for (int o = 32; o > 0; o >>= 1) w += __shfl_down(w, o, 64);
    if (tid == 0) dsum_s = w;
  }
  const int d = tid & 127, h = tid >> 7;
  float a = 0.f;
  const float* op = opart + (size_t)g * NC * D + d;
#pragma unroll 8
  for (int ch = h * 32; ch < h * 32 + 32; ++ch) a += op[ch * D];
  red[tid] = a;
  __syncthreads();
  if (tid < D) out[g * D + tid] = (red[tid] + red[tid + 128]) / dsum_s;
}

extern "C" void kernel_launch(void* const* d_in, const int* in_sizes, int n_in,
                              void* d_out, int out_size, void* d_ws,
                              size_t ws_size, hipStream_t stream) {
  const float* x = (const float*)d_in[0];
  const int* mask = (const int*)d_in[1];
  const float* Wq = (const float*)d_in[2];
  const float* bq = (const float*)d_in[3];
  const float* Wk = (const float*)d_in[4];
  const float* bk = (const float*)d_in[5];
  float* out = (float*)d_out;

  float* ws = (float*)d_ws;
  float* meanacc = ws;                  // G*D
  float* qt = ws + G * D;               // G*D
  float* cvec = ws + 2 * G * D;         // G
  float* fcnt = ws + 2 * G * D + G;     // G
  float* opart = ws + 2 * G * D + 2 * G;  // G*NC*D (4 MB)
  float* dpart = opart + (size_t)G * NC * D;  // G*NC

  k1_mean<<<G * 32, 256, 0, stream>>>(x, mask, meanacc, fcnt);
  k2_query<<<G, 128, 0, stream>>>(meanacc, fcnt, Wq, bq, Wk, bk, qt, cvec);
  k3_fused<<<G * NC, 256, 0, stream>>>(x, mask, qt, cvec, opart, dpart);
  k4_reduce<<<G, 256, 0, stream>>>(opart, dpart, out);
}

// Round 3
// 417.107 us; speedup vs baseline: 1.0461x; 1.0039x over previous
//
#include <hip/hip_runtime.h>
#include <math.h>

// B=8, N=16, D=128, H=W=64 -> G=128 groups, K=4096 tokens/group.
// keys GEMM collapses: attn_k = q_tilde.x_k + c, q_tilde = Wk^T(Wq mean+bq),
// c = query.bk. Logits ~ +-1 -> no-max softmax safe. Two x passes (mean needs
// all of x before logits exist; softmax nonlinearity makes the re-read
// irreducible) -- ~400 MB HBM floor ~= 65 us. dur_us also carries ~320 us of
// harness 1-GiB workspace poison fills (not controllable).
//
// HARD-WON RULE (R5: 1238us, R6: 650us vs R4: ~136us kernel time): NO
// agent-scope acquire/release fences -- they L2-writeback/invalidate per use
// on non-coherent XCD L2s. All cross-block dataflow via kernel boundaries.
//
// R7: k3 x-tile in registers across barriers (LDS 41.5->14.8KB): neutral
// (-3us) -> k3 was not LDS-bound.
// R8: ZERO atomics (opart/dpart partials + k4 reduce): -14us, matched
// prediction -- cross-XCD atomic RMW serialization was real.
// R9 (this round): latency trims. k2 -> 256 threads, split-K halves both
// serial 128-FMA dot chains. k3 stages qt[g] in LDS (1 coalesced 512B read
// replaces 2M per-lane scalar gathers) with x-loads issued before the
// staging barrier. k2-into-k1 finisher fusion rejected: done-counter needs
// zero-init but ws is poisoned with an unknown pattern each iteration.
#define G 128
#define D 128
#define K 4096
#define CK 64
#define NC (K / CK)  // 64 chunks per group

// k1: meanacc[g][d] = sum_k mask[g][k]*x[g][d][k].  One wave per d-row,
// 16 float4 x-loads fma'd against int4 mask loads (L1-shared by the 4 waves).
// No LDS -> occupancy at wave cap. Each wave covers the whole 16KB mask row,
// so block s==0 wave 0 reduces its int partials into fcnt[g] for free.
__global__ __launch_bounds__(256) void k1_mean(const float* __restrict__ x,
                                               const int* __restrict__ mask,
                                               float* __restrict__ meanacc,
                                               float* __restrict__ fcnt) {
  const int g = blockIdx.x >> 5, s = blockIdx.x & 31;
  const int tid = threadIdx.x;
  const int wid = tid >> 6, lane = tid & 63;
  const int d = s * 4 + wid;
  const float4* x4 = (const float4*)(x + ((size_t)g * D + d) * K);
  const int4* m4 = (const int4*)(mask + (size_t)g * K);
  float4 acc = make_float4(0.f, 0.f, 0.f, 0.f);
  int cs = 0;
#pragma unroll
  for (int it = 0; it < K / 256; ++it) {  // 16 iterations
    float4 a = x4[it * 64 + lane];
    int4 mi = m4[it * 64 + lane];
    acc.x += a.x * (float)mi.x;
    acc.y += a.y * (float)mi.y;
    acc.z += a.z * (float)mi.z;
    acc.w += a.w * (float)mi.w;
    cs += mi.x + mi.y + mi.z + mi.w;
  }
  float sum = acc.x + acc.y + acc.z + acc.w;
#pragma unroll
  for (int o = 32; o > 0; o >>= 1) sum += __shfl_down(sum, o, 64);
  if (lane == 0) meanacc[g * D + d] = sum;
  if (s == 0 && wid == 0) {  // wave 0 spans all 1024 int4s of the mask row
#pragma unroll
    for (int o = 32; o > 0; o >>= 1) cs += __shfl_down(cs, o, 64);
    if (lane == 0) fcnt[g] = (float)cs;
  }
}

// k2: per group: mean, query = Wq*mean+bq, qt = Wk^T query, c = query.bk.
// 256 threads, split-K: thread (o = t&127, h = t>>7) covers d-half
// [64h, 64h+64) of each dot; halves the serial FMA chains and doubles
// latency hiding on this 128-block (latency-bound) launch.
__global__ __launch_bounds__(256) void k2_query(
    const float* __restrict__ meanacc, const float* __restrict__ fcnt,
    const float* __restrict__ Wq, const float* __restrict__ bq,
    const float* __restrict__ Wk, const float* __restrict__ bk,
    float* __restrict__ qt, float* __restrict__ cvec) {
  __shared__ __align__(16) float mean_s[D];
  __shared__ float query_s[D];
  __shared__ float red[256];
  const int g = blockIdx.x, t = threadIdx.x;
  const int o = t & 127, h = t >> 7;
  if (t < D) mean_s[t] = meanacc[g * D + t] / fcnt[g];
  __syncthreads();
  {  // Wq matvec (row-major, per-thread contiguous float4)
    float p = 0.f;
    const float4* wq4 = (const float4*)(Wq + (size_t)o * D + 64 * h);
    const float4* ms4 = (const float4*)(mean_s + 64 * h);
#pragma unroll
    for (int dc = 0; dc < 16; ++dc) {
      float4 w = wq4[dc], m = ms4[dc];
      p += w.x * m.x + w.y * m.y + w.z * m.z + w.w * m.w;
    }
    red[t] = p;
  }
  __syncthreads();
  float q = 0.f;
  if (t < D) {
    q = red[t] + red[t + 128] + bq[t];
    query_s[t] = q;
  }
  __syncthreads();
  if (t < D) red[t] = q * bk[t];  // cvec partial (tree below touches t<128)
  __syncthreads();
  for (int off = 64; off > 0; off >>= 1) {
    if (t < off) red[t] += red[t + off];
    __syncthreads();
  }
  if (t == 0) cvec[g] = red[0];
  float qq = 0.f;  // Wk^T matvec (coalesced across o)
#pragma unroll 8
  for (int d = 64 * h; d < 64 * h + 64; ++d)
    qq += query_s[d] * Wk[(size_t)d * D + o];
  __syncthreads();  // red reuse guard
  red[t] = qq;
  __syncthreads();
  if (t < D) qt[g * D + t] = red[t] + red[t + 128];
}

// k3: fused logits + exp + pool. Block = (g, 64-k chunk), g DESCENDING
// (serpentine vs k1 for L3 reuse). Thread (j=tid&15, owner=tid>>4) owns
// k-quad 4j..4j+3 and d-rows owner+16*it (it=0..7); the 8 float4 x values
// stay in REGISTERS across all barriers -- no xs LDS tile.
//   phase 0: issue all 8 x-loads; stage qt[g] -> qts (1 coalesced 512B read)
//   phase 1: accumulate logit partials vs qts (LDS, no VMEM gathers)
//   phase 2: 64 threads combine 16 owner-partials, mask+exp -> wsm;
//            denom partial -> dpart[g][chunk] (plain store)
//   phase 3: per-thread 4-FMA pool partial -> part3[d][j]; 128 threads
//            reduce rows via b128 -> opart[g][chunk][d] (plain store).
// part2 pad 17: write banks 2-way (free). part3 pad 20: b128-aligned rows.
__global__ __launch_bounds__(256) void k3_fused(
    const float* __restrict__ x, const int* __restrict__ mask,
    const float* __restrict__ qt, const float* __restrict__ cvec,
    float* __restrict__ opart, float* __restrict__ dpart) {
  __shared__ float part2[CK][17];                  // [k][owner] logit partials
  __shared__ __align__(16) float wsm[CK];          // softmax weights
  __shared__ __align__(16) float part3[D][20];     // [d][j] pool partials
  __shared__ __align__(16) float qts[D];           // staged q_tilde
  const int g = (G - 1) - (int)(blockIdx.x >> 6);  // serpentine
  const int bc = blockIdx.x & 63;
  const int k0 = bc * CK;
  const int tid = threadIdx.x;
  const int j = tid & 15, owner = tid >> 4;
  const float4* xg = (const float4*)(x + (size_t)g * D * K + k0);
  float4 v[8];
#pragma unroll
  for (int it = 0; it < 8; ++it)
    v[it] = xg[(size_t)(owner + 16 * it) * (K / 4) + j];
  if (tid < D) qts[tid] = qt[g * D + tid];
  __syncthreads();
  float p0 = 0.f, p1 = 0.f, p2 = 0.f, p3 = 0.f;
#pragma unroll
  for (int it = 0; it < 8; ++it) {
    const float qv = qts[owner + 16 * it];
    p0 += qv * v[it].x;
    p1 += qv * v[it].y;
    p2 += qv * v[it].z;
    p3 += qv * v[it].w;
  }
  part2[4 * j + 0][owner] = p0;
  part2[4 * j + 1][owner] = p1;
  part2[4 * j + 2][owner] = p2;
  part2[4 * j + 3][owner] = p3;
  __syncthreads();
  if (tid < CK) {  // combine 16 partials, exp, mask; denom partial store
    float l = 0.f;
#pragma unroll
    for (int o = 0; o < 16; ++o) l += part2[tid][o];
    const float scale = 0.08838834764831845f;  // 1/sqrt(128)
    l = (l + cvec[g]) * scale;
    float w = mask[(size_t)g * K + k0 + tid] ? __expf(l) : 0.f;
    wsm[tid] = w;
#pragma unroll
    for (int o = 32; o > 0; o >>= 1) w += __shfl_down(w, o, 64);
    if (tid == 0) dpart[g * NC + bc] = w;
  }
  __syncthreads();
  {  // pool partials straight from the register tile
    const float4 wv = *(const float4*)&wsm[4 * j];
#pragma unroll
    for (int it = 0; it < 8; ++it) {
      const int dd = owner + 16 * it;
      part3[dd][j] =
          wv.x * v[it].x + wv.y * v[it].y + wv.z * v[it].z + wv.w * v[it].w;
    }
  }
  __syncthreads();
  if (tid < D) {  // reduce 16 j-partials per d-row, b128 conflict-free
    const float4* r4 = (const float4*)part3[tid];
    float4 a = r4[0], b = r4[1], c = r4[2], e = r4[3];
    float o = a.x + a.y + a.z + a.w + b.x + b.y + b.z + b.w + c.x + c.y + c.z +
              c.w + e.x + e.y + e.z + e.w;
    opart[(size_t)(g * NC + bc) * D + tid] = o;
  }
}

// k4: per group, reduce 64 chunk-partials and normalize.
// Reads 32KB/block coalesced (256B rows, 512B stride); 4MB total.
__global__ __launch_bounds__(256) void k4_reduce(
    const float* __restrict__ opart, const float* __restrict__ dpart,
    float* __restrict__ out) {
  __shared__ float red[256];
  __shared__ float dsum_s;
  const int g = blockIdx.x, tid = threadIdx.x;
  if (tid < 64) {  // wave 0: denominator
    float w = dpart[g * NC + tid];
#pragma unroll
    for (int o = 32; o > 0; o >>= 1) w += __shfl_down(w, o, 64);
    if (tid == 0) dsum_s = w;
  }
  const int d = tid & 127, h = tid >> 7;
  float a = 0.f;
  const float* op = opart + (size_t)g * NC * D + d;
#pragma unroll 8
  for (int ch = h * 32; ch < h * 32 + 32; ++ch) a += op[ch * D];
  red[tid] = a;
  __syncthreads();
  if (tid < D) out[g * D + tid] = (red[tid] + red[tid + 128]) / dsum_s;
}

extern "C" void kernel_launch(void* const* d_in, const int* in_sizes, int n_in,
                              void* d_out, int out_size, void* d_ws,
                              size_t ws_size, hipStream_t stream) {
  const float* x = (const float*)d_in[0];
  const int* mask = (const int*)d_in[1];
  const float* Wq = (const float*)d_in[2];
  const float* bq = (const float*)d_in[3];
  const float* Wk = (const float*)d_in[4];
  const float* bk = (const float*)d_in[5];
  float* out = (float*)d_out;

  float* ws = (float*)d_ws;
  float* meanacc = ws;                        // G*D
  float* qt = ws + G * D;                     // G*D
  float* cvec = ws + 2 * G * D;               // G
  float* fcnt = ws + 2 * G * D + G;           // G
  float* opart = ws + 2 * G * D + 2 * G;      // G*NC*D (4 MB)
  float* dpart = opart + (size_t)G * NC * D;  // G*NC

  k1_mean<<<G * 32, 256, 0, stream>>>(x, mask, meanacc, fcnt);
  k2_query<<<G, 256, 0, stream>>>(meanacc, fcnt, Wq, bq, Wk, bk, qt, cvec);
  k3_fused<<<G * NC, 256, 0, stream>>>(x, mask, qt, cvec, opart, dpart);
  k4_reduce<<<G, 256, 0, stream>>>(opart, dpart, out);
}